// Round 10
// baseline (386.468 us; speedup 1.0000x reference)
//
#include <hip/hip_runtime.h>
#include <cstdint>

// ---------------------------------------------------------------------------
// SarvamMoEAttention fused block for MI355X (gfx950).
// Pipeline: f32->bf16 conv | QKV GEMM (256^2 pipelined) | RMSNorm+RoPE |
//           flash attn (causal, GQA 16q/4kv, D=128) | out GEMM -> f32.
// R4: gemm256: 256x256 tile, BK=64, 8 waves, 2-slot LDS dbuf, 4-phase K-loop
//     with burst prefetch + single vmcnt(0) drain per K-tile; attn: diagonal-
//     only masking, exp2-domain softmax, defer-rescale (T13).
// (6th resubmission — R4..R9 benches all hit GPUAcquisitionTimeout)
// ---------------------------------------------------------------------------

#define DEVI __device__ __forceinline__

typedef float  f32x4  __attribute__((ext_vector_type(4)));
typedef __bf16 bf16x8 __attribute__((ext_vector_type(8)));
typedef __bf16 bf16x4 __attribute__((ext_vector_type(4)));

// async global->LDS, 16B per lane; LDS dest = wave-uniform base + lane*16.
DEVI void gload16(const void* g, void* l) {
  __builtin_amdgcn_global_load_lds(
      (const __attribute__((address_space(1))) void*)g,
      (__attribute__((address_space(3))) void*)l, 16, 0, 0);
}

// ---------------------------------------------------------------------------
// 1) fp32 -> bf16 elementwise conversion
// ---------------------------------------------------------------------------
__global__ __launch_bounds__(256) void cvt_bf16(const float* __restrict__ in,
                                                __bf16* __restrict__ out,
                                                long n) {
  long i = ((long)blockIdx.x * 256 + threadIdx.x) * 4;
  if (i >= n) return;
  f32x4 v = *(const f32x4*)(in + i);
  bf16x4 o;
  o[0] = (__bf16)v[0]; o[1] = (__bf16)v[1];
  o[2] = (__bf16)v[2]; o[3] = (__bf16)v[3];
  *(bf16x4*)(out + i) = o;
}

// ---------------------------------------------------------------------------
// 2/5) gemm256: C[M][N] = sum_k A[m][k]*B[n][k]  (bf16, B^T form)
// 256x256 tile, BK=64, 512 threads = 8 waves (2M x 4N), per-wave 128x64 out.
// LDS (dynamic 128 KiB): [slot2][A/B][half2][128 rows][64 cols] bf16, 16B
// chunks XOR-swizzled by (row&7), staged via global_load_lds with
// inverse-swizzled global source (linear LDS dest).
// Per K-tile: 4 phases x 16 MFMA; phase 0 bursts the next tile's 8 staging
// loads into the free slot; one vmcnt(0) drain at phase 3 (4 phases of cover).
// ---------------------------------------------------------------------------
#define STAGE256(SLOT) do {                                           \
    char* dst_ = ldsw + (SLOT)*65536 + w*1024;                        \
    gload16(pA00, dst_ + 0);     gload16(pA01, dst_ + 8192);          \
    gload16(pA10, dst_ + 16384); gload16(pA11, dst_ + 24576);         \
    gload16(pB00, dst_ + 32768); gload16(pB01, dst_ + 40960);         \
    gload16(pB10, dst_ + 49152); gload16(pB11, dst_ + 57344);         \
    pA00 += 64; pA01 += 64; pA10 += 64; pA11 += 64;                   \
    pB00 += 64; pB01 += 64; pB10 += 64; pB11 += 64;                   \
  } while (0)

#define LOAD_A256(MH)                                                     \
  _Pragma("unroll") for (int m = 0; m < 4; ++m)                           \
  _Pragma("unroll") for (int ks = 0; ks < 2; ++ks)                        \
    Ar[m][ks] = *(const bf16x8*)(aB + ((MH)*64 + m*16)*128 + coff[ks]);

#define LOAD_B256(NH)                                                     \
  _Pragma("unroll") for (int n = 0; n < 2; ++n)                           \
  _Pragma("unroll") for (int ks = 0; ks < 2; ++ks)                        \
    Br[(NH)*2 + n][ks] =                                                  \
        *(const bf16x8*)(bB + ((NH)*32 + n*16)*128 + coff[ks]);

#define MFMA_QUAD256(MH, NH)                                              \
  __builtin_amdgcn_s_setprio(1);                                          \
  _Pragma("unroll") for (int m = 0; m < 4; ++m)                           \
  _Pragma("unroll") for (int n = 0; n < 2; ++n)                           \
  _Pragma("unroll") for (int ks = 0; ks < 2; ++ks)                        \
    acc[(MH)*4 + m][(NH)*2 + n] =                                         \
        __builtin_amdgcn_mfma_f32_16x16x32_bf16(                          \
            Ar[m][ks], Br[(NH)*2 + n][ks], acc[(MH)*4 + m][(NH)*2 + n],   \
            0, 0, 0);                                                     \
  __builtin_amdgcn_s_setprio(0);

template <typename CT>
__global__ __launch_bounds__(512, 2) void gemm256(const __bf16* __restrict__ A,
                                                  const __bf16* __restrict__ B,
                                                  CT* __restrict__ C,
                                                  int M, int N, int K) {
  extern __shared__ char ldsw[];  // 131072 B
  const int tid = threadIdx.x;
  const int l = tid & 63, w = tid >> 6;    // 8 waves
  const int wr = w >> 2, wc = w & 3;       // 2 x 4
  const int g = l >> 4, li = l & 15;

  // XCD swizzle (bijective: nwg % 8 == 0)
  const int nbx = gridDim.x;
  const int nwg = nbx * gridDim.y;
  const int orig = blockIdx.y * nbx + blockIdx.x;
  const int swz = (orig & 7) * (nwg >> 3) + (orig >> 3);
  const int bx = swz % nbx, by = swz / nbx;
  const long rowBase = (long)by * 256;
  const long colBase = (long)bx * 256;

  // staging source pointers: lane row-in-8 = l>>3, src chunk = (l&7)^(l>>3)
  const int lr = l >> 3;
  const int lc = (l & 7) ^ lr;
  const long ar = rowBase + w * 8 + lr;
  const long br = colBase + w * 8 + lr;
  const __bf16* pA00 = A + (ar)       * (long)K + lc * 8;
  const __bf16* pA01 = A + (ar + 64)  * (long)K + lc * 8;
  const __bf16* pA10 = A + (ar + 128) * (long)K + lc * 8;
  const __bf16* pA11 = A + (ar + 192) * (long)K + lc * 8;
  const __bf16* pB00 = B + (br)       * (long)K + lc * 8;
  const __bf16* pB01 = B + (br + 64)  * (long)K + lc * 8;
  const __bf16* pB10 = B + (br + 128) * (long)K + lc * 8;
  const __bf16* pB11 = B + (br + 192) * (long)K + lc * 8;

  // ds_read swizzled chunk offsets (row&7 == li&7 for all fragment rows)
  int coff[2];
  coff[0] = ((0 + g) ^ (li & 7)) * 16;
  coff[1] = ((4 + g) ^ (li & 7)) * 16;

  f32x4 acc[8][4];
#pragma unroll
  for (int i = 0; i < 8; ++i)
#pragma unroll
    for (int j = 0; j < 4; ++j) acc[i][j] = f32x4{0.f, 0.f, 0.f, 0.f};

  // prologue: stage tile 0 into slot 0
  STAGE256(0);
  asm volatile("s_waitcnt vmcnt(0)" ::: "memory");
  __builtin_amdgcn_sched_barrier(0);
  __builtin_amdgcn_s_barrier();

  const int nkt = K >> 6;
  for (int t = 0; t < nkt; ++t) {
    const int slot = t & 1;
    const char* aB = ldsw + slot * 65536 + wr * 16384 + li * 128;
    const char* bB = ldsw + slot * 65536 + 32768 + (wc >> 1) * 16384 +
                     (wc & 1) * 8192 + li * 128;
    bf16x8 Ar[4][2], Br[4][2];

    // phase 0: A(mh0) + B(nh0) reads; burst-prefetch next tile
    LOAD_A256(0);
    LOAD_B256(0);
    if (t + 1 < nkt) STAGE256(slot ^ 1);
    __builtin_amdgcn_s_barrier();
    MFMA_QUAD256(0, 0);

    // phase 1: B(nh1) reads
    LOAD_B256(1);
    __builtin_amdgcn_s_barrier();
    MFMA_QUAD256(0, 1);

    // phase 2: A(mh1) reads
    LOAD_A256(1);
    __builtin_amdgcn_s_barrier();
    MFMA_QUAD256(1, 0);

    // phase 3: no reads
    __builtin_amdgcn_s_barrier();
    MFMA_QUAD256(1, 1);

    if (t + 1 < nkt) {
      asm volatile("s_waitcnt vmcnt(0)" ::: "memory");  // next tile landed
      __builtin_amdgcn_sched_barrier(0);
    }
    __builtin_amdgcn_s_barrier();
  }

  // C write: row = rowBase+wr*128+mf*16+g*4+r, col = colBase+wc*64+nf*16+li
  const long rb = rowBase + wr * 128 + g * 4;
  const long cb = colBase + wc * 64 + li;
#pragma unroll
  for (int mf = 0; mf < 8; ++mf)
#pragma unroll
    for (int nf = 0; nf < 4; ++nf)
#pragma unroll
      for (int r = 0; r < 4; ++r)
        C[(rb + mf * 16 + r) * (long)N + cb + nf * 16] = (CT)acc[mf][nf][r];
}

// ---------------------------------------------------------------------------
// 3) RMSNorm + RoPE. One wave per (token, head-of-24). qkv bf16 [4096][3072].
// Q -> [b][16][s][128], K -> [b][4][s][128], V -> TRANSPOSED [b][4][128][s]
// ---------------------------------------------------------------------------
__global__ __launch_bounds__(256) void normrope(
    const __bf16* __restrict__ qkv, const float* __restrict__ cosb,
    const float* __restrict__ sinb, const float* __restrict__ qw,
    const float* __restrict__ kw, __bf16* __restrict__ Qo,
    __bf16* __restrict__ Ko, __bf16* __restrict__ Vt) {
  const int tid = threadIdx.x, l = tid & 63, w = tid >> 6;
  const int pair = blockIdx.x * 4 + w;
  const int t = pair / 24, hh = pair % 24;
  const __bf16* src = qkv + (long)t * 3072 + hh * 128 + 2 * l;
  float x0 = (float)src[0], x1 = (float)src[1];

  if (hh < 20) {
    float ss = x0 * x0 + x1 * x1;
#pragma unroll
    for (int off = 1; off < 64; off <<= 1) ss += __shfl_xor(ss, off);
    const float rs = rsqrtf(ss * (1.0f / 128.0f) + 1e-6f);
    const float* wn = (hh < 16) ? qw : kw;
    x0 = x0 * rs * wn[2 * l];
    x1 = x1 * rs * wn[2 * l + 1];
    float y0 = __shfl_xor(x0, 16);
    float y1 = __shfl_xor(x1, 16);
    if (l < 32) {
      float c0 = cosb[(long)t * 64 + 2 * l], c1 = cosb[(long)t * 64 + 2 * l + 1];
      float s0 = sinb[(long)t * 64 + 2 * l], s1 = sinb[(long)t * 64 + 2 * l + 1];
      if (l < 16) { x0 = x0 * c0 - y0 * s0; x1 = x1 * c1 - y1 * s1; }
      else        { x0 = x0 * c0 + y0 * s0; x1 = x1 * c1 + y1 * s1; }
    }
  }
  const int b = t >> 11, sIdx = t & 2047;
  if (hh < 16) {
    __bf16* dst = Qo + (((long)(b * 16 + hh)) * 2048 + sIdx) * 128 + 2 * l;
    dst[0] = (__bf16)x0; dst[1] = (__bf16)x1;
  } else if (hh < 20) {
    __bf16* dst = Ko + (((long)(b * 4 + hh - 16)) * 2048 + sIdx) * 128 + 2 * l;
    dst[0] = (__bf16)x0; dst[1] = (__bf16)x1;
  } else {
    __bf16* dst = Vt + (((long)(b * 4 + hh - 20)) * 128 + 2 * l) * 2048 + sIdx;
    dst[0] = (__bf16)x0; dst[2048] = (__bf16)x1;
  }
}

// ---------------------------------------------------------------------------
// 4) Flash attention, causal, GQA, paired q-tiles + dbuf pipeline.
// R4: diagonal-only mask, exp2-domain softmax, defer-rescale (T13).
// ---------------------------------------------------------------------------
DEVI void stage_kv(const __bf16* Kp, const __bf16* Vp, int kv0,
                   __bf16* Kl, __bf16* Vl, int tid, int w) {
#pragma unroll
  for (int it = 0; it < 4; ++it) {
    int ci = it * 256 + tid;
    int row = ci >> 4, c = ci & 15;
    gload16(Kp + (long)(kv0 + row) * 128 + (c ^ (row & 7)) * 8,
            (char*)Kl + it * 4096 + w * 1024);
  }
#pragma unroll
  for (int it = 0; it < 4; ++it) {
    int ci = it * 256 + tid;
    int row = ci >> 3, c = ci & 7;
    gload16(Vp + (long)row * 2048 + kv0 + (c ^ (row & 7)) * 8,
            (char*)Vl + it * 4096 + w * 1024);
  }
}

__global__ __launch_bounds__(256) void attn_kernel(
    const __bf16* __restrict__ Q, const __bf16* __restrict__ Kg,
    const __bf16* __restrict__ Vg, __bf16* __restrict__ Aout) {
  __shared__ __bf16 Klds[2][8192];  // [64 kv][128 d], swizzled, dbuf
  __shared__ __bf16 Vlds[2][8192];  // [128 d][64 kv], swizzled, dbuf
  __shared__ __bf16 Plds[4096];     // per-wave [16 q][64 kv], swizzled
  const int tid = threadIdx.x, l = tid & 63, w = tid >> 6;
  const int pr = blockIdx.x, h = blockIdx.y, b = blockIdx.z;
  const int kvh = h >> 2;
  const int g = l >> 4, li = l & 15;
  const __bf16* Kp = Kg + ((long)(b * 4 + kvh)) * 2048 * 128;
  const __bf16* Vp = Vg + ((long)(b * 4 + kvh)) * 128 * 2048;  // d-major

  const float SCL = 0.12751649736f;     // 1/sqrt(128) * log2(e)
  const float THR = 11.5415603f;        // 8 nats in log2 units

  for (int seg = 0; seg < 2; ++seg) {
    const int qt = seg ? (31 - pr) : pr;
    const int q0 = qt * 64;
    const int nt = qt + 1;

    const __bf16* Qp =
        Q + (((long)(b * 16 + h)) * 2048 + q0 + w * 16 + li) * 128 + g * 8;
    bf16x8 qf[4];
#pragma unroll
    for (int ks = 0; ks < 4; ++ks) qf[ks] = *(const bf16x8*)(Qp + ks * 32);

    f32x4 o[8];
#pragma unroll
    for (int d = 0; d < 8; ++d) o[d] = f32x4{0.f, 0.f, 0.f, 0.f};
    float mrow[4], lrow[4];
#pragma unroll
    for (int r = 0; r < 4; ++r) { mrow[r] = -__builtin_inff(); lrow[r] = 0.f; }

    __builtin_amdgcn_s_barrier();
    stage_kv(Kp, Vp, 0, Klds[0], Vlds[0], tid, w);

    for (int kt = 0; kt < nt; ++kt) {
      const int cur = kt & 1;
      const int kv0 = kt * 64;
      __builtin_amdgcn_s_barrier();  // A: buf cur^1 free for overwrite
      if (kt + 1 < nt) {
        stage_kv(Kp, Vp, kv0 + 64, Klds[cur ^ 1], Vlds[cur ^ 1], tid, w);
        asm volatile("s_waitcnt vmcnt(8)" ::: "memory");  // tile kt landed
      } else {
        asm volatile("s_waitcnt vmcnt(0)" ::: "memory");
      }
      __builtin_amdgcn_s_barrier();  // B: tile kt visible to all waves
      __builtin_amdgcn_sched_barrier(0);

      const __bf16* Kl = Klds[cur];
      const __bf16* Vl = Vlds[cur];

      // --- QK^T: S[q16][kv64] per wave ---
      f32x4 s[4];
#pragma unroll
      for (int nf = 0; nf < 4; ++nf) s[nf] = f32x4{0.f, 0.f, 0.f, 0.f};
      __builtin_amdgcn_s_setprio(1);
#pragma unroll
      for (int nf = 0; nf < 4; ++nf) {
        const char* kb = (const char*)Kl + (nf * 16 + li) * 256;
#pragma unroll
        for (int ks = 0; ks < 4; ++ks) {
          bf16x8 kf = *(const bf16x8*)(kb + ((((ks << 2) + g) ^ (l & 7)) << 4));
          s[nf] = __builtin_amdgcn_mfma_f32_16x16x32_bf16(qf[ks], kf, s[nf], 0, 0, 0);
        }
      }
      __builtin_amdgcn_s_setprio(0);

      // scale (exp2 domain); causal mask only on the diagonal tile
      if (kt == qt) {
        const int qg = q0 + w * 16 + (g << 2);
#pragma unroll
        for (int nf = 0; nf < 4; ++nf) {
          int kvg = kv0 + nf * 16 + li;
#pragma unroll
          for (int r = 0; r < 4; ++r) {
            float sv = s[nf][r] * SCL;
            s[nf][r] = (kvg <= qg + r) ? sv : -__builtin_inff();
          }
        }
      } else {
#pragma unroll
        for (int nf = 0; nf < 4; ++nf)
#pragma unroll
          for (int r = 0; r < 4; ++r) s[nf][r] *= SCL;
      }

      // online softmax (log2 domain), defer-rescale when max growth <= THR
      float mx[4];
#pragma unroll
      for (int r = 0; r < 4; ++r) {
        mx[r] = fmaxf(fmaxf(s[0][r], s[1][r]), fmaxf(s[2][r], s[3][r]));
        mx[r] = fmaxf(mx[r], __shfl_xor(mx[r], 1));
        mx[r] = fmaxf(mx[r], __shfl_xor(mx[r], 2));
        mx[r] = fmaxf(mx[r], __shfl_xor(mx[r], 4));
        mx[r] = fmaxf(mx[r], __shfl_xor(mx[r], 8));
      }
      bool need = (mx[0] > mrow[0] + THR) || (mx[1] > mrow[1] + THR) ||
                  (mx[2] > mrow[2] + THR) || (mx[3] > mrow[3] + THR);
      if (__any(need)) {
#pragma unroll
        for (int r = 0; r < 4; ++r) {
          float mn = fmaxf(mrow[r], mx[r]);
          float alpha = exp2f(mrow[r] - mn);
          mrow[r] = mn;
          lrow[r] *= alpha;
#pragma unroll
          for (int d = 0; d < 8; ++d) o[d][r] *= alpha;
        }
      }
      float rsum[4] = {0.f, 0.f, 0.f, 0.f};
#pragma unroll
      for (int nf = 0; nf < 4; ++nf)
#pragma unroll
        for (int r = 0; r < 4; ++r) {
          float p = exp2f(s[nf][r] - mrow[r]);
          s[nf][r] = p;
          rsum[r] += p;
        }
#pragma unroll
      for (int r = 0; r < 4; ++r) {
        rsum[r] += __shfl_xor(rsum[r], 1);
        rsum[r] += __shfl_xor(rsum[r], 2);
        rsum[r] += __shfl_xor(rsum[r], 4);
        rsum[r] += __shfl_xor(rsum[r], 8);
        lrow[r] += rsum[r];
      }

      // write P (bf16) to per-wave swizzled LDS
      char* pw = (char*)Plds + w * 2048;
#pragma unroll
      for (int nf = 0; nf < 4; ++nf)
#pragma unroll
        for (int r = 0; r < 4; ++r) {
          int qr = (g << 2) + r;
          int off = (qr * 128 + (nf * 16 + li) * 2) ^ ((qr & 7) << 4);
          *(__bf16*)(pw + off) = (__bf16)s[nf][r];
        }

      // --- PV: O[q16][d128] += P[q16][kv] * V[kv][d] ---
      __builtin_amdgcn_s_setprio(1);
#pragma unroll
      for (int kvs = 0; kvs < 2; ++kvs) {
        const bf16x8 pf = *(const bf16x8*)(
            (const char*)Plds + w * 2048 + li * 128 +
            ((((kvs << 2) + g) ^ (l & 7)) << 4));
#pragma unroll
        for (int d = 0; d < 8; ++d) {
          int dd = d * 16 + li;
          const bf16x8 vf = *(const bf16x8*)(
              (const char*)Vl + dd * 128 + ((((kvs << 2) + g) ^ (li & 7)) << 4));
          o[d] = __builtin_amdgcn_mfma_f32_16x16x32_bf16(pf, vf, o[d], 0, 0, 0);
        }
      }
      __builtin_amdgcn_s_setprio(0);
    }

    // epilogue
    __bf16* op = Aout + ((long)(b * 2048 + q0 + w * 16 + (g << 2))) * 2048 +
                 h * 128 + li;
#pragma unroll
    for (int r = 0; r < 4; ++r) {
      float inv = 1.0f / lrow[r];
#pragma unroll
      for (int d = 0; d < 8; ++d)
        op[(long)r * 2048 + d * 16] = (__bf16)(o[d][r] * inv);
    }
  }
}

// ---------------------------------------------------------------------------
// launch
// ---------------------------------------------------------------------------
extern "C" void kernel_launch(void* const* d_in, const int* in_sizes, int n_in,
                              void* d_out, int out_size, void* d_ws,
                              size_t ws_size, hipStream_t stream) {
  const float* hidden = (const float*)d_in[0];
  const float* cosb = (const float*)d_in[2];
  const float* sinb = (const float*)d_in[3];
  const float* Wqkv = (const float*)d_in[4];
  const float* qw   = (const float*)d_in[5];
  const float* kw   = (const float*)d_in[6];
  const float* Wd   = (const float*)d_in[7];
  float* out = (float*)d_out;
  char* ws = (char*)d_ws;

  __bf16* hb   = (__bf16*)(ws);                       // 16 MiB  (phase 1)
  __bf16* wqb  = (__bf16*)(ws + 16777216);            // 12 MiB  (phase 1)
  __bf16* Qb   = (__bf16*)(ws);                       // 16 MiB  (phase 2)
  __bf16* Kb   = (__bf16*)(ws + 16777216);            // 4 MiB   (phase 2)
  __bf16* Vb   = (__bf16*)(ws + 20971520);            // 4 MiB   (phase 2)
  __bf16* qkvb = (__bf16*)(ws + 29360128);            // 24 MiB  (phase 1)
  __bf16* aout = (__bf16*)(ws + 29360128);            // 16 MiB  (phase 2)
  __bf16* wdb  = (__bf16*)(ws + 54525952);            // 8 MiB

  cvt_bf16<<<8192, 256, 0, stream>>>(hidden, hb, 8388608L);
  cvt_bf16<<<6144, 256, 0, stream>>>(Wqkv, wqb, 6291456L);
  cvt_bf16<<<4096, 256, 0, stream>>>(Wd, wdb, 4194304L);
  gemm256<__bf16><<<dim3(12, 16), 512, 131072, stream>>>(hb, wqb, qkvb,
                                                         4096, 3072, 2048);
  normrope<<<24576, 256, 0, stream>>>(qkvb, cosb, sinb, qw, kw, Qb, Kb, Vb);
  attn_kernel<<<dim3(16, 16, 2), 256, 0, stream>>>(Qb, Kb, Vb, aout);
  gemm256<float><<<dim3(8, 16), 512, 131072, stream>>>(aout, wdb, out,
                                                       4096, 2048, 2048);
}

// Round 11
// 360.098 us; speedup vs baseline: 1.0732x; 1.0732x over previous
//
#include <hip/hip_runtime.h>
#include <cstdint>

// ---------------------------------------------------------------------------
// SarvamMoEAttention fused block for MI355X (gfx950).
// R11: gemm256<CT,NF>: BN=NF*64 (QKV NF=3 -> 192, grid 256 blocks = 100% CU;
//      out NF=2 -> 128, grid 256). K-loop uses attn-style counted vmcnt:
//      stage(t+1) at tile top, vmcnt(NLOADS) so tile t's loads (issued one
//      full tile earlier, ~800cy cover) are landed; no per-tile drain.
//      V-transpose split out of normrope into LDS-tile transpose kernel.
// ---------------------------------------------------------------------------

#define DEVI __device__ __forceinline__

typedef float  f32x4  __attribute__((ext_vector_type(4)));
typedef __bf16 bf16x8 __attribute__((ext_vector_type(8)));
typedef __bf16 bf16x4 __attribute__((ext_vector_type(4)));

// async global->LDS, 16B per lane; LDS dest = wave-uniform base + lane*16.
DEVI void gload16(const void* g, void* l) {
  __builtin_amdgcn_global_load_lds(
      (const __attribute__((address_space(1))) void*)g,
      (__attribute__((address_space(3))) void*)l, 16, 0, 0);
}

// ---------------------------------------------------------------------------
// 1) fp32 -> bf16 elementwise conversion
// ---------------------------------------------------------------------------
__global__ __launch_bounds__(256) void cvt_bf16(const float* __restrict__ in,
                                                __bf16* __restrict__ out,
                                                long n) {
  long i = ((long)blockIdx.x * 256 + threadIdx.x) * 4;
  if (i >= n) return;
  f32x4 v = *(const f32x4*)(in + i);
  bf16x4 o;
  o[0] = (__bf16)v[0]; o[1] = (__bf16)v[1];
  o[2] = (__bf16)v[2]; o[3] = (__bf16)v[3];
  *(bf16x4*)(out + i) = o;
}

// ---------------------------------------------------------------------------
// 2/5) gemm256<CT,NF>: C[M][N] = sum_k A[m][k]*B[n][k]  (bf16, B^T form)
// Tile 256 x (NF*64), BK=64, 512 threads = 8 waves (2M x 4N),
// per-wave out 128 x (NF*16). LDS: 2 slots x (4+NF) x 8KB 64-row blocks,
// 16B chunks XOR-swizzled by (row&7); staged via global_load_lds with
// inverse-swizzled global source.
// Per K-tile: top {barrier; STAGE(t+1); vmcnt(4+NF); barrier} then 4 phases
// {frag ds_reads; barrier; setprio MFMA}. Loads for tile t were issued at
// tile t-1's top -> one full tile (~800cy) of latency cover.
// ---------------------------------------------------------------------------
#define STAGE_T(SLOTIDX) do {                                         \
    char* dst_ = ldsw + (SLOTIDX) * SLOT_BYTES + w * 1024;            \
    _Pragma("unroll") for (int i_ = 0; i_ < 4; ++i_) {                \
      gload16(pA[i_], dst_ + i_ * 8192); pA[i_] += 64; }              \
    _Pragma("unroll") for (int j_ = 0; j_ < NF; ++j_) {               \
      gload16(pB[j_], dst_ + 32768 + j_ * 8192); pB[j_] += 64; }      \
  } while (0)

#define LOADA_T(MH)                                                       \
  _Pragma("unroll") for (int m = 0; m < 4; ++m)                           \
  _Pragma("unroll") for (int ks = 0; ks < 2; ++ks)                        \
    Ar[m][ks] = *(const bf16x8*)(aB + (MH) * 8192 + m * 2048 + coff[ks]);

#define LOADB_T(NFROM, NCNT)                                              \
  _Pragma("unroll") for (int n = 0; n < (NCNT); ++n)                      \
  _Pragma("unroll") for (int ks = 0; ks < 2; ++ks) {                      \
    int c16 = wc * NF + (NFROM) + n;                                      \
    Br[(NFROM) + n][ks] = *(const bf16x8*)(                               \
        bB + (c16 >> 2) * 8192 + (c16 & 3) * 2048 + coff[ks]);            \
  }

#define MFMA_T(MH, NFROM, NCNT)                                           \
  __builtin_amdgcn_s_setprio(1);                                          \
  _Pragma("unroll") for (int m = 0; m < 4; ++m)                           \
  _Pragma("unroll") for (int n = 0; n < (NCNT); ++n)                      \
  _Pragma("unroll") for (int ks = 0; ks < 2; ++ks)                        \
    acc[(MH)*4 + m][(NFROM) + n] =                                        \
        __builtin_amdgcn_mfma_f32_16x16x32_bf16(                          \
            Ar[m][ks], Br[(NFROM) + n][ks], acc[(MH)*4 + m][(NFROM) + n], \
            0, 0, 0);                                                     \
  __builtin_amdgcn_s_setprio(0);

template <typename CT, int NF>
__global__ __launch_bounds__(512, 2) void gemm256(const __bf16* __restrict__ A,
                                                  const __bf16* __restrict__ B,
                                                  CT* __restrict__ C,
                                                  int M, int N, int K) {
  constexpr int NLOADS = 4 + NF;               // gload instrs per tile
  constexpr int SLOT_BYTES = NLOADS * 8192;
  constexpr int G0 = (NF == 3) ? 2 : 1;        // phase n-split
  extern __shared__ char ldsw[];
  const int tid = threadIdx.x;
  const int l = tid & 63, w = tid >> 6;        // 8 waves
  const int wr = w >> 2, wc = w & 3;           // 2 x 4
  const int g = l >> 4, li = l & 15;

  // XCD swizzle (bijective: nwg % 8 == 0; both grids are 256)
  const int nbx = gridDim.x;
  const int nwg = nbx * gridDim.y;
  const int orig = blockIdx.y * nbx + blockIdx.x;
  const int swz = (orig & 7) * (nwg >> 3) + (orig >> 3);
  const int bx = swz % nbx, by = swz / nbx;
  const long rowBase = (long)by * 256;
  const long colBase = (long)bx * (NF * 64);

  // staging source pointers: per 64-row block, row = w*8 + (l>>3),
  // src chunk = (l&7)^(row&7)  (dest LDS linear)
  const int lr = l >> 3;
  const int lc = (l & 7) ^ lr;
  const __bf16* pA[4];
  const __bf16* pB[NF];
#pragma unroll
  for (int i = 0; i < 4; ++i)
    pA[i] = A + (rowBase + i * 64 + w * 8 + lr) * (long)K + lc * 8;
#pragma unroll
  for (int j = 0; j < NF; ++j)
    pB[j] = B + (colBase + j * 64 + w * 8 + lr) * (long)K + lc * 8;

  // ds_read swizzled chunk offsets (row&7 == li&7 for all fragment rows)
  int coff[2];
  coff[0] = ((0 + g) ^ (li & 7)) * 16;
  coff[1] = ((4 + g) ^ (li & 7)) * 16;

  f32x4 acc[8][NF];
#pragma unroll
  for (int i = 0; i < 8; ++i)
#pragma unroll
    for (int j = 0; j < NF; ++j) acc[i][j] = f32x4{0.f, 0.f, 0.f, 0.f};

  // prologue: issue tile 0 into slot 0 (loads stay in flight)
  STAGE_T(0);

  const int nkt = K >> 6;
  for (int t = 0; t < nkt; ++t) {
    const int slot = t & 1;
    __builtin_amdgcn_s_barrier();  // A: slot^1 free for overwrite
    if (t + 1 < nkt) {
      STAGE_T(slot ^ 1);           // issue tile t+1 (NLOADS instrs)
      if constexpr (NLOADS == 7)
        asm volatile("s_waitcnt vmcnt(7)" ::: "memory");  // tile t landed
      else
        asm volatile("s_waitcnt vmcnt(6)" ::: "memory");
    } else {
      asm volatile("s_waitcnt vmcnt(0)" ::: "memory");
    }
    __builtin_amdgcn_sched_barrier(0);
    __builtin_amdgcn_s_barrier();  // B: tile t visible

    const char* aB = ldsw + slot * SLOT_BYTES + wr * 2 * 8192 + li * 128;
    const char* bB = ldsw + slot * SLOT_BYTES + 32768 + li * 128;
    bf16x8 Ar[4][2], Br[NF][2];

    // ph0
    LOADA_T(0);
    LOADB_T(0, G0);
    __builtin_amdgcn_s_barrier();
    MFMA_T(0, 0, G0);
    // ph1
    LOADB_T(G0, NF - G0);
    __builtin_amdgcn_s_barrier();
    MFMA_T(0, G0, NF - G0);
    // ph2
    LOADA_T(1);
    __builtin_amdgcn_s_barrier();
    MFMA_T(1, 0, G0);
    // ph3
    __builtin_amdgcn_s_barrier();
    MFMA_T(1, G0, NF - G0);
  }

  // C write: row = rowBase+wr*128+mf*16+g*4+r, col = colBase+wc*16*NF+nf*16+li
  const long rb = rowBase + wr * 128 + g * 4;
  const long cb = colBase + wc * (16 * NF) + li;
#pragma unroll
  for (int mf = 0; mf < 8; ++mf)
#pragma unroll
    for (int nf = 0; nf < NF; ++nf)
#pragma unroll
      for (int r = 0; r < 4; ++r)
        C[(rb + mf * 16 + r) * (long)N + cb + nf * 16] = (CT)acc[mf][nf][r];
}

// ---------------------------------------------------------------------------
// 3) RMSNorm + RoPE for Q,K heads only (V handled by vtrans).
// One wave per (token, head-of-20). qkv bf16 [4096][3072].
// Q -> [b][16][s][128], K -> [b][4][s][128]
// ---------------------------------------------------------------------------
__global__ __launch_bounds__(256) void normrope(
    const __bf16* __restrict__ qkv, const float* __restrict__ cosb,
    const float* __restrict__ sinb, const float* __restrict__ qw,
    const float* __restrict__ kw, __bf16* __restrict__ Qo,
    __bf16* __restrict__ Ko) {
  const int tid = threadIdx.x, l = tid & 63, w = tid >> 6;
  const int pair = blockIdx.x * 4 + w;       // 81920 total
  const int t = pair / 20, hh = pair % 20;
  const __bf16* src = qkv + (long)t * 3072 + hh * 128 + 2 * l;
  float x0 = (float)src[0], x1 = (float)src[1];

  float ss = x0 * x0 + x1 * x1;
#pragma unroll
  for (int off = 1; off < 64; off <<= 1) ss += __shfl_xor(ss, off);
  const float rs = rsqrtf(ss * (1.0f / 128.0f) + 1e-6f);
  const float* wn = (hh < 16) ? qw : kw;
  x0 = x0 * rs * wn[2 * l];
  x1 = x1 * rs * wn[2 * l + 1];
  float y0 = __shfl_xor(x0, 16);
  float y1 = __shfl_xor(x1, 16);
  if (l < 32) {
    float c0 = cosb[(long)t * 64 + 2 * l], c1 = cosb[(long)t * 64 + 2 * l + 1];
    float s0 = sinb[(long)t * 64 + 2 * l], s1 = sinb[(long)t * 64 + 2 * l + 1];
    if (l < 16) { x0 = x0 * c0 - y0 * s0; x1 = x1 * c1 - y1 * s1; }
    else        { x0 = x0 * c0 + y0 * s0; x1 = x1 * c1 + y1 * s1; }
  }
  const int b = t >> 11, sIdx = t & 2047;
  if (hh < 16) {
    __bf16* dst = Qo + (((long)(b * 16 + hh)) * 2048 + sIdx) * 128 + 2 * l;
    dst[0] = (__bf16)x0; dst[1] = (__bf16)x1;
  } else {
    __bf16* dst = Ko + (((long)(b * 4 + hh - 16)) * 2048 + sIdx) * 128 + 2 * l;
    dst[0] = (__bf16)x0; dst[1] = (__bf16)x1;
  }
}

// ---------------------------------------------------------------------------
// 3b) V transpose: qkv [4096][3072] V-part -> Vt [b][kvh][128][2048].
// LDS 64x64 tile; coalesced 128B global reads and writes.
// ---------------------------------------------------------------------------
__global__ __launch_bounds__(256) void vtrans(const __bf16* __restrict__ qkv,
                                              __bf16* __restrict__ Vt) {
  __shared__ __bf16 tl[64][72];  // pad to 72 to spread banks on column read
  const int st = blockIdx.x, dh = blockIdx.y, bh = blockIdx.z;
  const int b = bh >> 2, kvh = bh & 3;
  const int t = threadIdx.x;
  // load: thread (tok = t>>2, dg = t&3) reads 2x16B
  {
    const int tok = t >> 2, dg = t & 3;
    const __bf16* src = qkv + ((long)b * 2048 + st * 64 + tok) * 3072 +
                        (20 + kvh) * 128 + dh * 64;
    *(bf16x8*)&tl[tok][dg * 8]      = *(const bf16x8*)(src + dg * 8);
    *(bf16x8*)&tl[tok][32 + dg * 8] = *(const bf16x8*)(src + 32 + dg * 8);
  }
  __syncthreads();
  // store: thread (dr = t>>2, sg = t&3) writes 2x16B of d-row dr
  {
    const int dr = t >> 2, sg = t & 3;
    __bf16* dst = Vt + (((long)bh * 128) + dh * 64 + dr) * 2048 +
                  (long)st * 64 + sg * 16;
    bf16x8 v0, v1;
#pragma unroll
    for (int j = 0; j < 8; ++j) {
      v0[j] = tl[sg * 16 + j][dr];
      v1[j] = tl[sg * 16 + 8 + j][dr];
    }
    *(bf16x8*)dst = v0;
    *(bf16x8*)(dst + 8) = v1;
  }
}

// ---------------------------------------------------------------------------
// 4) Flash attention, causal, GQA, paired q-tiles + dbuf pipeline (unchanged).
// ---------------------------------------------------------------------------
DEVI void stage_kv(const __bf16* Kp, const __bf16* Vp, int kv0,
                   __bf16* Kl, __bf16* Vl, int tid, int w) {
#pragma unroll
  for (int it = 0; it < 4; ++it) {
    int ci = it * 256 + tid;
    int row = ci >> 4, c = ci & 15;
    gload16(Kp + (long)(kv0 + row) * 128 + (c ^ (row & 7)) * 8,
            (char*)Kl + it * 4096 + w * 1024);
  }
#pragma unroll
  for (int it = 0; it < 4; ++it) {
    int ci = it * 256 + tid;
    int row = ci >> 3, c = ci & 7;
    gload16(Vp + (long)row * 2048 + kv0 + (c ^ (row & 7)) * 8,
            (char*)Vl + it * 4096 + w * 1024);
  }
}

__global__ __launch_bounds__(256) void attn_kernel(
    const __bf16* __restrict__ Q, const __bf16* __restrict__ Kg,
    const __bf16* __restrict__ Vg, __bf16* __restrict__ Aout) {
  __shared__ __bf16 Klds[2][8192];  // [64 kv][128 d], swizzled, dbuf
  __shared__ __bf16 Vlds[2][8192];  // [128 d][64 kv], swizzled, dbuf
  __shared__ __bf16 Plds[4096];     // per-wave [16 q][64 kv], swizzled
  const int tid = threadIdx.x, l = tid & 63, w = tid >> 6;
  const int pr = blockIdx.x, h = blockIdx.y, b = blockIdx.z;
  const int kvh = h >> 2;
  const int g = l >> 4, li = l & 15;
  const __bf16* Kp = Kg + ((long)(b * 4 + kvh)) * 2048 * 128;
  const __bf16* Vp = Vg + ((long)(b * 4 + kvh)) * 128 * 2048;  // d-major

  const float SCL = 0.12751649736f;     // 1/sqrt(128) * log2(e)
  const float THR = 11.5415603f;        // 8 nats in log2 units

  for (int seg = 0; seg < 2; ++seg) {
    const int qt = seg ? (31 - pr) : pr;
    const int q0 = qt * 64;
    const int nt = qt + 1;

    const __bf16* Qp =
        Q + (((long)(b * 16 + h)) * 2048 + q0 + w * 16 + li) * 128 + g * 8;
    bf16x8 qf[4];
#pragma unroll
    for (int ks = 0; ks < 4; ++ks) qf[ks] = *(const bf16x8*)(Qp + ks * 32);

    f32x4 o[8];
#pragma unroll
    for (int d = 0; d < 8; ++d) o[d] = f32x4{0.f, 0.f, 0.f, 0.f};
    float mrow[4], lrow[4];
#pragma unroll
    for (int r = 0; r < 4; ++r) { mrow[r] = -__builtin_inff(); lrow[r] = 0.f; }

    __builtin_amdgcn_s_barrier();
    stage_kv(Kp, Vp, 0, Klds[0], Vlds[0], tid, w);

    for (int kt = 0; kt < nt; ++kt) {
      const int cur = kt & 1;
      const int kv0 = kt * 64;
      __builtin_amdgcn_s_barrier();  // A: buf cur^1 free for overwrite
      if (kt + 1 < nt) {
        stage_kv(Kp, Vp, kv0 + 64, Klds[cur ^ 1], Vlds[cur ^ 1], tid, w);
        asm volatile("s_waitcnt vmcnt(8)" ::: "memory");  // tile kt landed
      } else {
        asm volatile("s_waitcnt vmcnt(0)" ::: "memory");
      }
      __builtin_amdgcn_s_barrier();  // B: tile kt visible to all waves
      __builtin_amdgcn_sched_barrier(0);

      const __bf16* Kl = Klds[cur];
      const __bf16* Vl = Vlds[cur];

      // --- QK^T ---
      f32x4 s[4];
#pragma unroll
      for (int nf = 0; nf < 4; ++nf) s[nf] = f32x4{0.f, 0.f, 0.f, 0.f};
      __builtin_amdgcn_s_setprio(1);
#pragma unroll
      for (int nf = 0; nf < 4; ++nf) {
        const char* kb = (const char*)Kl + (nf * 16 + li) * 256;
#pragma unroll
        for (int ks = 0; ks < 4; ++ks) {
          bf16x8 kf = *(const bf16x8*)(kb + ((((ks << 2) + g) ^ (l & 7)) << 4));
          s[nf] = __builtin_amdgcn_mfma_f32_16x16x32_bf16(qf[ks], kf, s[nf], 0, 0, 0);
        }
      }
      __builtin_amdgcn_s_setprio(0);

      // scale; causal mask only on diagonal tile
      if (kt == qt) {
        const int qg = q0 + w * 16 + (g << 2);
#pragma unroll
        for (int nf = 0; nf < 4; ++nf) {
          int kvg = kv0 + nf * 16 + li;
#pragma unroll
          for (int r = 0; r < 4; ++r) {
            float sv = s[nf][r] * SCL;
            s[nf][r] = (kvg <= qg + r) ? sv : -__builtin_inff();
          }
        }
      } else {
#pragma unroll
        for (int nf = 0; nf < 4; ++nf)
#pragma unroll
          for (int r = 0; r < 4; ++r) s[nf][r] *= SCL;
      }

      // online softmax (log2 domain), defer-rescale
      float mx[4];
#pragma unroll
      for (int r = 0; r < 4; ++r) {
        mx[r] = fmaxf(fmaxf(s[0][r], s[1][r]), fmaxf(s[2][r], s[3][r]));
        mx[r] = fmaxf(mx[r], __shfl_xor(mx[r], 1));
        mx[r] = fmaxf(mx[r], __shfl_xor(mx[r], 2));
        mx[r] = fmaxf(mx[r], __shfl_xor(mx[r], 4));
        mx[r] = fmaxf(mx[r], __shfl_xor(mx[r], 8));
      }
      bool need = (mx[0] > mrow[0] + THR) || (mx[1] > mrow[1] + THR) ||
                  (mx[2] > mrow[2] + THR) || (mx[3] > mrow[3] + THR);
      if (__any(need)) {
#pragma unroll
        for (int r = 0; r < 4; ++r) {
          float mn = fmaxf(mrow[r], mx[r]);
          float alpha = exp2f(mrow[r] - mn);
          mrow[r] = mn;
          lrow[r] *= alpha;
#pragma unroll
          for (int d = 0; d < 8; ++d) o[d][r] *= alpha;
        }
      }
      float rsum[4] = {0.f, 0.f, 0.f, 0.f};
#pragma unroll
      for (int nf = 0; nf < 4; ++nf)
#pragma unroll
        for (int r = 0; r < 4; ++r) {
          float p = exp2f(s[nf][r] - mrow[r]);
          s[nf][r] = p;
          rsum[r] += p;
        }
#pragma unroll
      for (int r = 0; r < 4; ++r) {
        rsum[r] += __shfl_xor(rsum[r], 1);
        rsum[r] += __shfl_xor(rsum[r], 2);
        rsum[r] += __shfl_xor(rsum[r], 4);
        rsum[r] += __shfl_xor(rsum[r], 8);
        lrow[r] += rsum[r];
      }

      // write P (bf16) to per-wave swizzled LDS
      char* pw = (char*)Plds + w * 2048;
#pragma unroll
      for (int nf = 0; nf < 4; ++nf)
#pragma unroll
        for (int r = 0; r < 4; ++r) {
          int qr = (g << 2) + r;
          int off = (qr * 128 + (nf * 16 + li) * 2) ^ ((qr & 7) << 4);
          *(__bf16*)(pw + off) = (__bf16)s[nf][r];
        }

      // --- PV ---
      __builtin_amdgcn_s_setprio(1);
#pragma unroll
      for (int kvs = 0; kvs < 2; ++kvs) {
        const bf16x8 pf = *(const bf16x8*)(
            (const char*)Plds + w * 2048 + li * 128 +
            ((((kvs << 2) + g) ^ (l & 7)) << 4));
#pragma unroll
        for (int d = 0; d < 8; ++d) {
          int dd = d * 16 + li;
          const bf16x8 vf = *(const bf16x8*)(
              (const char*)Vl + dd * 128 + ((((kvs << 2) + g) ^ (li & 7)) << 4));
          o[d] = __builtin_amdgcn_mfma_f32_16x16x32_bf16(pf, vf, o[d], 0, 0, 0);
        }
      }
      __builtin_amdgcn_s_setprio(0);
    }

    // epilogue
    __bf16* op = Aout + ((long)(b * 2048 + q0 + w * 16 + (g << 2))) * 2048 +
                 h * 128 + li;
#pragma unroll
    for (int r = 0; r < 4; ++r) {
      float inv = 1.0f / lrow[r];
#pragma unroll
      for (int d = 0; d < 8; ++d)
        op[(long)r * 2048 + d * 16] = (__bf16)(o[d][r] * inv);
    }
  }
}

// ---------------------------------------------------------------------------
// launch
// ---------------------------------------------------------------------------
extern "C" void kernel_launch(void* const* d_in, const int* in_sizes, int n_in,
                              void* d_out, int out_size, void* d_ws,
                              size_t ws_size, hipStream_t stream) {
  const float* hidden = (const float*)d_in[0];
  const float* cosb = (const float*)d_in[2];
  const float* sinb = (const float*)d_in[3];
  const float* Wqkv = (const float*)d_in[4];
  const float* qw   = (const float*)d_in[5];
  const float* kw   = (const float*)d_in[6];
  const float* Wd   = (const float*)d_in[7];
  float* out = (float*)d_out;
  char* ws = (char*)d_ws;

  __bf16* hb   = (__bf16*)(ws);                       // 16 MiB  (phase 1)
  __bf16* wqb  = (__bf16*)(ws + 16777216);            // 12 MiB  (phase 1)
  __bf16* Qb   = (__bf16*)(ws);                       // 16 MiB  (phase 2)
  __bf16* Kb   = (__bf16*)(ws + 16777216);            // 4 MiB   (phase 2)
  __bf16* Vb   = (__bf16*)(ws + 20971520);            // 4 MiB   (phase 2)
  __bf16* qkvb = (__bf16*)(ws + 29360128);            // 24 MiB  (phase 1)
  __bf16* aout = (__bf16*)(ws + 29360128);            // 16 MiB  (phase 2)
  __bf16* wdb  = (__bf16*)(ws + 54525952);            // 8 MiB

  cvt_bf16<<<8192, 256, 0, stream>>>(hidden, hb, 8388608L);
  cvt_bf16<<<6144, 256, 0, stream>>>(Wqkv, wqb, 6291456L);
  cvt_bf16<<<4096, 256, 0, stream>>>(Wd, wdb, 4194304L);
  // QKV GEMM: 256x192 tiles -> 16x16 = 256 blocks (100% CU fill)
  gemm256<__bf16, 3><<<dim3(16, 16), 512, 114688, stream>>>(hb, wqb, qkvb,
                                                            4096, 3072, 2048);
  // RMSNorm+RoPE (Q,K) and V transpose
  normrope<<<20480, 256, 0, stream>>>(qkvb, cosb, sinb, qw, kw, Qb, Kb);
  vtrans<<<dim3(32, 2, 8), 256, 0, stream>>>(qkvb, Vb);
  attn_kernel<<<dim3(16, 16, 2), 256, 0, stream>>>(Qb, Kb, Vb, aout);
  // out GEMM: 256x128 tiles -> 16x16 = 256 blocks
  gemm256<float, 2><<<dim3(16, 16), 512, 98304, stream>>>(aout, wdb, out,
                                                          4096, 2048, 2048);
}